// Round 6
// baseline (276.502 us; speedup 1.0000x reference)
//
#include <hip/hip_runtime.h>

typedef __bf16 bf16;
typedef __bf16 bf16x8 __attribute__((ext_vector_type(8)));
typedef float floatx4 __attribute__((ext_vector_type(4)));

#define NB 2
#define NS 2048
#define ND 1024
#define NH 16
#define NDK 64
#define NM (NB * NS)   // 4096 rows

// async global->LDS, 16B per lane, dest = wave-uniform base + lane*16
__device__ __forceinline__ void async_cp16(const void* g, void* l) {
  __builtin_amdgcn_global_load_lds(
      (const __attribute__((address_space(1))) void*)g,
      (__attribute__((address_space(3))) void*)l, 16, 0, 0);
}

__device__ __forceinline__ bf16x8 cvt8(const float* p) {
  float4 lo = *(const float4*)p, hi = *(const float4*)(p + 4);
  bf16x8 o;
  o[0] = (bf16)lo.x; o[1] = (bf16)lo.y; o[2] = (bf16)lo.z; o[3] = (bf16)lo.w;
  o[4] = (bf16)hi.x; o[5] = (bf16)hi.y; o[6] = (bf16)hi.z; o[7] = (bf16)hi.w;
  return o;
}

// ---------------------------------------------------------------------------
// fp32 -> bf16 conversion, multi-segment in one dispatch
// ---------------------------------------------------------------------------
struct CvtArgs {
  const float* src[8];
  bf16* dst[8];
  int nblk[8];
  int nseg;
};

__global__ __launch_bounds__(256) void cvt_kernel(CvtArgs a) {
  int b = blockIdx.x, seg = 0;
  while (seg < a.nseg - 1 && b >= a.nblk[seg]) { b -= a.nblk[seg]; ++seg; }
  const size_t idx = ((size_t)b * 256 + threadIdx.x) * 8;
  *(bf16x8*)(a.dst[seg] + idx) = cvt8(a.src[seg] + idx);
}

// ---------------------------------------------------------------------------
// C[m][n] = sum_k A[m][k] * W[n][k] + bias[n]   (NT GEMM, W bf16)
// ---------------------------------------------------------------------------
template <int TM, typename TA, typename TC>
__global__ __launch_bounds__(256) void gemm_dma(
    const TA* __restrict__ A0, const TA* __restrict__ A1, const TA* __restrict__ A2,
    const bf16* __restrict__ W0, const bf16* __restrict__ W1, const bf16* __restrict__ W2,
    const float* __restrict__ bias0, const float* __restrict__ bias1, const float* __restrict__ bias2,
    TC* __restrict__ C0, TC* __restrict__ C1, TC* __restrict__ C2)
{
  const int z = blockIdx.z;
  const TA* A = (z == 0) ? A0 : (z == 1) ? A1 : A2;
  const bf16* W = (z == 0) ? W0 : (z == 1) ? W1 : W2;
  const float* bias = (z == 0) ? bias0 : (z == 1) ? bias1 : bias2;
  TC* C = (z == 0) ? C0 : (z == 1) ? C1 : C2;

  __shared__ bf16 At[TM * 32];
  __shared__ bf16 Bt[128 * 32];

  const int tid = threadIdx.x;
  const int wave = tid >> 6, lane = tid & 63;
  const int q4 = lane >> 4, l15 = lane & 15;
  const int m0 = blockIdx.y * TM, n0 = blockIdx.x * 128;
  constexpr int WM = TM / 2;
  constexpr int MI = WM / 16;
  const int wm = (wave >> 1) * WM, wn = (wave & 1) * 64;

  floatx4 acc[MI][4] = {};

  const bf16* Wg = W + (size_t)(n0 + (lane >> 2)) * ND + (lane & 3) * 8;
  const bf16* Ag = nullptr;
  const float* Af = nullptr;
  const int srow = tid >> 2, sk = (tid & 3) * 8;
  if constexpr (sizeof(TA) == 2)
    Ag = (const bf16*)A + (size_t)(m0 + (lane >> 2)) * ND + (lane & 3) * 8;
  else
    Af = (const float*)A + (size_t)(m0 + srow) * ND + sk;

  for (int k0 = 0; k0 < ND; k0 += 32) {
    bf16x8 a0, a1;
    if constexpr (sizeof(TA) == 4) {
      a0 = cvt8(Af + k0);
      if constexpr (TM == 128) a1 = cvt8(Af + (size_t)64 * ND + k0);
    }
    __syncthreads();
#pragma unroll
    for (int c2 = 0; c2 < 2; ++c2) {
      const int c = wave * 2 + c2;
      async_cp16(Wg + (size_t)c * 16 * ND + k0, &Bt[c * 16 * 32]);
    }
    if constexpr (sizeof(TA) == 2) {
#pragma unroll
      for (int c2 = 0; c2 < TM / 64; ++c2) {
        const int c = wave * (TM / 64) + c2;
        async_cp16(Ag + (size_t)c * 16 * ND + k0, &At[c * 16 * 32]);
      }
    } else {
      *(bf16x8*)&At[srow * 32 + sk] = a0;
      if constexpr (TM == 128) *(bf16x8*)&At[(srow + 64) * 32 + sk] = a1;
    }
    __syncthreads();

    bf16x8 af[MI], bfr[4];
#pragma unroll
    for (int i = 0; i < MI; ++i)
      af[i] = *(const bf16x8*)&At[(wm + i * 16 + l15) * 32 + q4 * 8];
#pragma unroll
    for (int j = 0; j < 4; ++j)
      bfr[j] = *(const bf16x8*)&Bt[(wn + j * 16 + l15) * 32 + q4 * 8];
#pragma unroll
    for (int i = 0; i < MI; ++i)
#pragma unroll
      for (int j = 0; j < 4; ++j)
        acc[i][j] = __builtin_amdgcn_mfma_f32_16x16x32_bf16(af[i], bfr[j], acc[i][j], 0, 0, 0);
  }

#pragma unroll
  for (int j = 0; j < 4; ++j) {
    const int col = n0 + wn + j * 16 + l15;
    const float bv = bias[col];
#pragma unroll
    for (int i = 0; i < MI; ++i) {
      const int rowb = m0 + wm + i * 16 + q4 * 4;
#pragma unroll
      for (int r = 0; r < 4; ++r)
        C[(size_t)(rowb + r) * ND + col] = (TC)(acc[i][j][r] + bv);
    }
  }
}

// ---------------------------------------------------------------------------
// Flash attention, causal, paired Q-tiles + SPLIT-K over 2 blocks.
// Grid (16, H, B*2): block (bx,h,z) with b=z&1, half=z>>1 processes Q-tiles
// {bx, 31-bx}, K-tiles restricted to its half: half0 = [0, ceil(n/2)),
// half1 = [ceil(n/2), n).  Fixed-max softmax -> partials purely additive:
// partial O (bf16, raw) + partial psum (fp32); combine kernel divides.
// Ping-pong register selection keyed on LOCAL iteration index jj (r5 bug:
// global-parity selection read uninitialized regs when js was odd).
// ---------------------------------------------------------------------------
#define LDV 72

__global__ __launch_bounds__(256) void attn_split(
    const bf16* __restrict__ Q, const bf16* __restrict__ K,
    const bf16* __restrict__ V, bf16* __restrict__ Oh0,
    bf16* __restrict__ Oh1, float* __restrict__ Ps)
{
  __shared__ bf16 vt[2][64 * LDV];
  __shared__ bf16 pbuf[4][16 * LDV];

  const int bx = blockIdx.x;
  const int h = blockIdx.y;
  const int b = blockIdx.z & 1, half = blockIdx.z >> 1;
  bf16* Oh = half ? Oh1 : Oh0;
  const int tid = threadIdx.x, wave = tid >> 6, lane = tid & 63;
  const int q4 = lane >> 4, l15 = lane & 15;
  const int sl = lane;
  const int dbase = wave * 8;

  const bf16* kp = K + ((size_t)(b * NS) + l15) * ND + h * NDK + q4 * 8;
  const bf16* vp = V + ((size_t)(b * NS) + sl) * ND + h * NDK + dbase;

  bf16x8 qf[2];
  floatx4 oacc[4];
  float psum[4];
  bf16x8 kA[8], vA[2], kB[8], vB[2];

  auto ldK = [&](int j, bf16x8 (&kk)[8]) {
    const bf16* p = kp + (size_t)j * (64 * ND);
#pragma unroll
    for (int nf = 0; nf < 4; ++nf)
#pragma unroll
      for (int t = 0; t < 2; ++t)
        kk[nf * 2 + t] = *(const bf16x8*)(p + (size_t)nf * 16 * ND + t * 32);
  };
  auto ldV = [&](int j, bf16x8 (&vv)[2]) {
    const bf16* p = vp + (size_t)j * (64 * ND);
    vv[0] = *(const bf16x8*)(p);
    vv[1] = *(const bf16x8*)(p + 32);
  };

  auto body = [&](int j, int iq, int je, bf16x8 (&kc)[8], bf16x8 (&vc)[2],
                  bf16x8 (&kn)[8], bf16x8 (&vn)[2]) {
    const int cur = j & 1;  // vt buffer: only needs to alternate
#pragma unroll
    for (int it = 0; it < 2; ++it)
#pragma unroll
      for (int e = 0; e < 8; ++e)
        vt[cur][(dbase + it * 32 + e) * LDV + sl] = vc[it][e];

    floatx4 sf[4];
#pragma unroll
    for (int nf = 0; nf < 4; ++nf) {
      floatx4 s = {0.f, 0.f, 0.f, 0.f};
      s = __builtin_amdgcn_mfma_f32_16x16x32_bf16(qf[0], kc[nf * 2 + 0], s, 0, 0, 0);
      s = __builtin_amdgcn_mfma_f32_16x16x32_bf16(qf[1], kc[nf * 2 + 1], s, 0, 0, 0);
      sf[nf] = s;
    }

    if (j + 1 < je) { ldK(j + 1, kn); ldV(j + 1, vn); }

    __syncthreads();  // vt[cur] staged by all waves

    if (j == iq) {  // causal mask on diagonal tile
#pragma unroll
      for (int nf = 0; nf < 4; ++nf) {
        const int kc2 = nf * 16 + l15;
#pragma unroll
        for (int r = 0; r < 4; ++r)
          if (kc2 > wave * 16 + q4 * 4 + r) sf[nf][r] = -1e30f;
      }
    }

#pragma unroll
    for (int nf = 0; nf < 4; ++nf)
#pragma unroll
      for (int r = 0; r < 4; ++r) {
        const float pv = exp2f(sf[nf][r]);
        psum[r] += pv;
        pbuf[wave][(q4 * 4 + r) * LDV + nf * 16 + l15] = (bf16)pv;
      }
    __asm__ __volatile__("s_waitcnt lgkmcnt(0)" ::: "memory");

#pragma unroll
    for (int nf = 0; nf < 4; ++nf)
#pragma unroll
      for (int t = 0; t < 2; ++t) {
        bf16x8 pa = *(const bf16x8*)&pbuf[wave][l15 * LDV + t * 32 + q4 * 8];
        bf16x8 vb = *(const bf16x8*)&vt[cur][(nf * 16 + l15) * LDV + t * 32 + q4 * 8];
        oacc[nf] = __builtin_amdgcn_mfma_f32_16x16x32_bf16(pa, vb, oacc[nf], 0, 0, 0);
      }
  };

  for (int ph = 0; ph < 2; ++ph) {
    const int iq = ph ? (31 - bx) : bx;
    const int n = iq + 1;
    const int h0 = (n + 1) >> 1;
    const int js = half ? h0 : 0;
    const int je = half ? n : h0;
    __syncthreads();  // protect vt from previous phase's readers

    const size_t qrow0 = (size_t)(b * NS + iq * 64 + wave * 16 + l15);
#pragma unroll
    for (int t = 0; t < 2; ++t) {
      bf16x8 tmp = *(const bf16x8*)(Q + qrow0 * ND + h * NDK + t * 32 + q4 * 8);
#pragma unroll
      for (int e = 0; e < 8; ++e) qf[t][e] = (bf16)((float)tmp[e] * 0.180336880f);
    }

#pragma unroll
    for (int nf = 0; nf < 4; ++nf) oacc[nf] = floatx4{0.f, 0.f, 0.f, 0.f};
#pragma unroll
    for (int r = 0; r < 4; ++r) psum[r] = 0.f;

    if (je > js) {
      ldK(js, kA); ldV(js, vA);   // initial tile ALWAYS lands in set A
      const int cnt = je - js;
      for (int jj = 0; jj < cnt; ++jj) {
        const int j = js + jj;
        if ((jj & 1) == 0) body(j, iq, je, kA, vA, kB, vB);  // local parity
        else               body(j, iq, je, kB, vB, kA, vA);
      }
    }

#pragma unroll
    for (int r = 0; r < 4; ++r)
#pragma unroll
      for (int off = 1; off < 16; off <<= 1) psum[r] += __shfl_xor(psum[r], off, 16);

    // store raw partials (no division)
#pragma unroll
    for (int nf = 0; nf < 4; ++nf)
#pragma unroll
      for (int r = 0; r < 4; ++r) {
        const int qrow = iq * 64 + wave * 16 + q4 * 4 + r;
        Oh[(size_t)(b * NS + qrow) * ND + h * NDK + nf * 16 + l15] = (bf16)oacc[nf][r];
      }
    if (l15 == 0) {
#pragma unroll
      for (int r = 0; r < 4; ++r) {
        const int qrow = iq * 64 + wave * 16 + q4 * 4 + r;
        Ps[(((size_t)half * NB + b) * NH + h) * NS + qrow] = psum[r];
      }
    }
  }
}

// combine: Ob = (O0 + O1) / (p0 + p1)
__global__ __launch_bounds__(256) void attn_combine(
    const bf16* __restrict__ Oh0, const bf16* __restrict__ Oh1,
    const float* __restrict__ Ps, bf16* __restrict__ Ob)
{
  const size_t g = (size_t)blockIdx.x * 256 + threadIdx.x;  // 8-col chunks
  const int row = (int)(g >> 7);            // 0..4095
  const int col = ((int)g & 127) * 8;       // 0..1023
  const int b = row >> 11, srow = row & (NS - 1);
  const int h = col >> 6;
  const float p0 = Ps[(((size_t)0 * NB + b) * NH + h) * NS + srow];
  const float p1 = Ps[(((size_t)1 * NB + b) * NH + h) * NS + srow];
  const float inv = 1.0f / (p0 + p1);
  const size_t off = (size_t)row * ND + col;
  bf16x8 o0 = *(const bf16x8*)(Oh0 + off);
  bf16x8 o1 = *(const bf16x8*)(Oh1 + off);
  bf16x8 o;
#pragma unroll
  for (int e = 0; e < 8; ++e) o[e] = (bf16)(((float)o0[e] + (float)o1[e]) * inv);
  *(bf16x8*)(Ob + off) = o;
}

// ---------------------------------------------------------------------------
// Legacy unsplit attention (round-4 known-good) for the <56MB fallback path.
// ---------------------------------------------------------------------------
__global__ __launch_bounds__(256) void attn_kernel(
    const bf16* __restrict__ Q, const bf16* __restrict__ K,
    const bf16* __restrict__ V, bf16* __restrict__ O)
{
  __shared__ bf16 vt[2][64 * LDV];
  __shared__ bf16 pbuf[4][16 * LDV];

  const int bx = blockIdx.x;
  const int h = blockIdx.y, b = blockIdx.z;
  const int tid = threadIdx.x, wave = tid >> 6, lane = tid & 63;
  const int q4 = lane >> 4, l15 = lane & 15;
  const int sl = lane;
  const int dbase = wave * 8;

  const bf16* kp = K + ((size_t)(b * NS) + l15) * ND + h * NDK + q4 * 8;
  const bf16* vp = V + ((size_t)(b * NS) + sl) * ND + h * NDK + dbase;

  bf16x8 qf[2];
  floatx4 oacc[4];
  float psum[4];
  bf16x8 kA[8], vA[2], kB[8], vB[2];

  auto ldK = [&](int j, bf16x8 (&kk)[8]) {
    const bf16* p = kp + (size_t)j * (64 * ND);
#pragma unroll
    for (int nf = 0; nf < 4; ++nf)
#pragma unroll
      for (int t = 0; t < 2; ++t)
        kk[nf * 2 + t] = *(const bf16x8*)(p + (size_t)nf * 16 * ND + t * 32);
  };
  auto ldV = [&](int j, bf16x8 (&vv)[2]) {
    const bf16* p = vp + (size_t)j * (64 * ND);
    vv[0] = *(const bf16x8*)(p);
    vv[1] = *(const bf16x8*)(p + 32);
  };

  auto body = [&](int j, int iq, bf16x8 (&kc)[8], bf16x8 (&vc)[2],
                  bf16x8 (&kn)[8], bf16x8 (&vn)[2]) {
    const int cur = j & 1;
#pragma unroll
    for (int it = 0; it < 2; ++it)
#pragma unroll
      for (int e = 0; e < 8; ++e)
        vt[cur][(dbase + it * 32 + e) * LDV + sl] = vc[it][e];

    floatx4 sf[4];
#pragma unroll
    for (int nf = 0; nf < 4; ++nf) {
      floatx4 s = {0.f, 0.f, 0.f, 0.f};
      s = __builtin_amdgcn_mfma_f32_16x16x32_bf16(qf[0], kc[nf * 2 + 0], s, 0, 0, 0);
      s = __builtin_amdgcn_mfma_f32_16x16x32_bf16(qf[1], kc[nf * 2 + 1], s, 0, 0, 0);
      sf[nf] = s;
    }

    if (j < iq) { ldK(j + 1, kn); ldV(j + 1, vn); }
    __syncthreads();

    if (j == iq) {
#pragma unroll
      for (int nf = 0; nf < 4; ++nf) {
        const int kc2 = nf * 16 + l15;
#pragma unroll
        for (int r = 0; r < 4; ++r)
          if (kc2 > wave * 16 + q4 * 4 + r) sf[nf][r] = -1e30f;
      }
    }

#pragma unroll
    for (int nf = 0; nf < 4; ++nf)
#pragma unroll
      for (int r = 0; r < 4; ++r) {
        const float pv = exp2f(sf[nf][r]);
        psum[r] += pv;
        pbuf[wave][(q4 * 4 + r) * LDV + nf * 16 + l15] = (bf16)pv;
      }
    __asm__ __volatile__("s_waitcnt lgkmcnt(0)" ::: "memory");

#pragma unroll
    for (int nf = 0; nf < 4; ++nf)
#pragma unroll
      for (int t = 0; t < 2; ++t) {
        bf16x8 pa = *(const bf16x8*)&pbuf[wave][l15 * LDV + t * 32 + q4 * 8];
        bf16x8 vb = *(const bf16x8*)&vt[cur][(nf * 16 + l15) * LDV + t * 32 + q4 * 8];
        oacc[nf] = __builtin_amdgcn_mfma_f32_16x16x32_bf16(pa, vb, oacc[nf], 0, 0, 0);
      }
  };

  for (int ph = 0; ph < 2; ++ph) {
    const int iq = ph ? (31 - bx) : bx;
    __syncthreads();

    const size_t qrow0 = (size_t)(b * NS + iq * 64 + wave * 16 + l15);
#pragma unroll
    for (int t = 0; t < 2; ++t) {
      bf16x8 tmp = *(const bf16x8*)(Q + qrow0 * ND + h * NDK + t * 32 + q4 * 8);
#pragma unroll
      for (int e = 0; e < 8; ++e) qf[t][e] = (bf16)((float)tmp[e] * 0.180336880f);
    }

#pragma unroll
    for (int nf = 0; nf < 4; ++nf) oacc[nf] = floatx4{0.f, 0.f, 0.f, 0.f};
#pragma unroll
    for (int r = 0; r < 4; ++r) psum[r] = 0.f;

    ldK(0, kA); ldV(0, vA);
    for (int j = 0; j <= iq; ++j) {
      if ((j & 1) == 0) body(j, iq, kA, vA, kB, vB);
      else              body(j, iq, kB, vB, kA, vA);
    }

#pragma unroll
    for (int r = 0; r < 4; ++r)
#pragma unroll
      for (int off = 1; off < 16; off <<= 1) psum[r] += __shfl_xor(psum[r], off, 16);

#pragma unroll
    for (int nf = 0; nf < 4; ++nf)
#pragma unroll
      for (int r = 0; r < 4; ++r) {
        const int qrow = iq * 64 + wave * 16 + q4 * 4 + r;
        O[(size_t)(b * NS + qrow) * ND + h * NDK + nf * 16 + l15] =
            (bf16)(oacc[nf][r] / psum[r]);
      }
  }
}

// ---------------------------------------------------------------------------
extern "C" void kernel_launch(void* const* d_in, const int* in_sizes, int n_in,
                              void* d_out, int out_size, void* d_ws, size_t ws_size,
                              hipStream_t stream) {
  const float* q  = (const float*)d_in[0];
  const float* k  = (const float*)d_in[1];
  const float* v  = (const float*)d_in[2];
  const float* Wq = (const float*)d_in[4];
  const float* bq = (const float*)d_in[5];
  const float* Wk = (const float*)d_in[6];
  const float* bk = (const float*)d_in[7];
  const float* Wv = (const float*)d_in[8];
  const float* bv = (const float*)d_in[9];
  const float* Wo = (const float*)d_in[10];
  const float* bo = (const float*)d_in[11];
  float* out = (float*)d_out;
  char* w = (char*)d_ws;

  if (ws_size >= (size_t)56 << 20) {
    bf16* xq = (bf16*)(w);
    bf16* xk = (bf16*)(w + ((size_t)8 << 20));
    bf16* xv = (bf16*)(w + ((size_t)16 << 20));
    bf16* wq = (bf16*)(w + ((size_t)24 << 20));
    bf16* wk = (bf16*)(w + ((size_t)26 << 20));
    bf16* wv = (bf16*)(w + ((size_t)28 << 20));
    bf16* wo = (bf16*)(w + ((size_t)30 << 20));
    bf16* Qb = (bf16*)(w + ((size_t)32 << 20));
    bf16* Kb = (bf16*)(w + ((size_t)40 << 20));
    bf16* Vb = (bf16*)(w + ((size_t)48 << 20));
    // after QKV GEMM: xk, xv, wq dead -> reuse for split-attention partials
    bf16* Oh0 = xk;
    bf16* Oh1 = xv;
    float* Ps = (float*)wq;   // 512 KB of the 2 MB wq region
    bf16* Ob = xq;            // xq dead after QKV GEMM

    CvtArgs ca{};
    const int b4 = (int)((size_t)NM * ND / 2048);
    const int b1 = (int)((size_t)ND * ND / 2048);
    ca.src[0] = q;  ca.dst[0] = xq; ca.nblk[0] = b4;
    ca.src[1] = k;  ca.dst[1] = xk; ca.nblk[1] = b4;
    ca.src[2] = v;  ca.dst[2] = xv; ca.nblk[2] = b4;
    ca.src[3] = Wq; ca.dst[3] = wq; ca.nblk[3] = b1;
    ca.src[4] = Wk; ca.dst[4] = wk; ca.nblk[4] = b1;
    ca.src[5] = Wv; ca.dst[5] = wv; ca.nblk[5] = b1;
    ca.src[6] = Wo; ca.dst[6] = wo; ca.nblk[6] = b1;
    ca.nseg = 7;
    cvt_kernel<<<3 * b4 + 4 * b1, 256, 0, stream>>>(ca);

    gemm_dma<128, bf16, bf16><<<dim3(8, 32, 3), 256, 0, stream>>>(
        xq, xk, xv, wq, wk, wv, bq, bk, bv, Qb, Kb, Vb);
    attn_split<<<dim3(16, NH, NB * 2), 256, 0, stream>>>(Qb, Kb, Vb, Oh0, Oh1, Ps);
    attn_combine<<<(int)((size_t)NM * ND / 8 / 256), 256, 0, stream>>>(Oh0, Oh1, Ps, Ob);
    gemm_dma<64, bf16, float><<<dim3(8, 64, 1), 256, 0, stream>>>(
        Ob, Ob, Ob, wo, wo, wo, bo, bo, bo, out, out, out);
  } else if (ws_size >= (size_t)40 << 20) {
    bf16* wq = (bf16*)(w);
    bf16* wk = (bf16*)(w + ((size_t)2 << 20));
    bf16* wv = (bf16*)(w + ((size_t)4 << 20));
    bf16* wo = (bf16*)(w + ((size_t)6 << 20));
    bf16* Qb = (bf16*)(w + ((size_t)8 << 20));
    bf16* Kb = (bf16*)(w + ((size_t)16 << 20));
    bf16* Vb = (bf16*)(w + ((size_t)24 << 20));
    bf16* Ob = (bf16*)(w + ((size_t)32 << 20));

    CvtArgs ca{};
    const int b1 = (int)((size_t)ND * ND / 2048);
    ca.src[0] = Wq; ca.dst[0] = wq; ca.nblk[0] = b1;
    ca.src[1] = Wk; ca.dst[1] = wk; ca.nblk[1] = b1;
    ca.src[2] = Wv; ca.dst[2] = wv; ca.nblk[2] = b1;
    ca.src[3] = Wo; ca.dst[3] = wo; ca.nblk[3] = b1;
    ca.nseg = 4;
    cvt_kernel<<<4 * b1, 256, 0, stream>>>(ca);

    gemm_dma<128, float, bf16><<<dim3(8, 32, 3), 256, 0, stream>>>(
        q, k, v, wq, wk, wv, bq, bk, bv, Qb, Kb, Vb);
    attn_kernel<<<dim3(16, NH, NB), 256, 0, stream>>>(Qb, Kb, Vb, Ob);
    gemm_dma<64, bf16, float><<<dim3(8, 64, 1), 256, 0, stream>>>(
        Ob, Ob, Ob, wo, wo, wo, bo, bo, bo, out, out, out);
  }
}